// Round 1
// baseline (1369.525 us; speedup 1.0000x reference)
//
#include <hip/hip_runtime.h>
#include <cstdint>
#include <cstddef>

#define BT_TOT 64000
#define FIN    1024
#define GV     640
#define NV     320
#define VD     128
#define INV_BT (1.0f/64000.0f)

// ---------------- GEMM: logits = X @ W^T + b  (fp32, vector ALU) ----------------
// BM=128, BN=128, BK=32, 256 threads, 8x8 per thread.
// LDS tiles stored transposed [k][row] so fragment reads are contiguous b128.
#define BMT 128
#define BNT 128
#define BKT 32
#define LDT 132   // 128 + 4 pad

__global__ __launch_bounds__(256) void gemm_logits(
    const float* __restrict__ X, const float* __restrict__ W,
    const float* __restrict__ bias, float* __restrict__ logits)
{
    __shared__ float As[BKT][LDT];   // As[k][m]
    __shared__ float Bs[BKT][LDT];   // Bs[k][n]
    const int tid = threadIdx.x;
    const int bn  = blockIdx.x;      // 0..4  (fastest-varying: co-resident blocks share X stripe via L3)
    const int bm  = blockIdx.y;      // 0..499
    const int m0  = bm * BMT, n0 = bn * BNT;
    const int tx  = tid & 15, ty = tid >> 4;

    float acc[8][8];
#pragma unroll
    for (int i = 0; i < 8; ++i)
#pragma unroll
        for (int j = 0; j < 8; ++j) acc[i][j] = 0.f;

    for (int k0 = 0; k0 < FIN; k0 += BKT) {
#pragma unroll
        for (int l = 0; l < 4; ++l) {
            const int idx = tid + 256 * l;
            const int row = idx >> 3;          // 0..127
            const int kq  = (idx & 7) << 2;    // 0,4,...,28
            const float4 xv = *(const float4*)(X + (size_t)(m0 + row) * FIN + (k0 + kq));
            As[kq+0][row] = xv.x; As[kq+1][row] = xv.y;
            As[kq+2][row] = xv.z; As[kq+3][row] = xv.w;
            const float4 wv = *(const float4*)(W + (size_t)(n0 + row) * FIN + (k0 + kq));
            Bs[kq+0][row] = wv.x; Bs[kq+1][row] = wv.y;
            Bs[kq+2][row] = wv.z; Bs[kq+3][row] = wv.w;
        }
        __syncthreads();
#pragma unroll
        for (int kk = 0; kk < BKT; ++kk) {
            float a[8], b[8];
            *(float4*)&a[0] = *(const float4*)&As[kk][4*ty];
            *(float4*)&a[4] = *(const float4*)&As[kk][64 + 4*ty];
            *(float4*)&b[0] = *(const float4*)&Bs[kk][4*tx];
            *(float4*)&b[4] = *(const float4*)&Bs[kk][64 + 4*tx];
#pragma unroll
            for (int i = 0; i < 8; ++i)
#pragma unroll
                for (int j = 0; j < 8; ++j)
                    acc[i][j] += a[i] * b[j];
        }
        __syncthreads();
    }

    // epilogue: add bias, store fp32 logits
    const float4 b0 = *(const float4*)(bias + n0 + 4*tx);
    const float4 b1 = *(const float4*)(bias + n0 + 64 + 4*tx);
#pragma unroll
    for (int i = 0; i < 8; ++i) {
        const int row = m0 + ((i < 4) ? (4*ty + i) : (64 + 4*ty + (i - 4)));
        float* dst = logits + (size_t)row * GV + n0;
        float4 o0, o1;
        o0.x = acc[i][0] + b0.x; o0.y = acc[i][1] + b0.y;
        o0.z = acc[i][2] + b0.z; o0.w = acc[i][3] + b0.w;
        o1.x = acc[i][4] + b1.x; o1.y = acc[i][5] + b1.y;
        o1.z = acc[i][6] + b1.z; o1.w = acc[i][7] + b1.w;
        *(float4*)(dst + 4*tx)      = o0;
        *(float4*)(dst + 64 + 4*tx) = o1;
    }
}

// ---------------- Row ops: argmaxes, softmax accumulation, codebook gather ----------------
// One wave per row; 4 waves/block; 64 rows/block; per-wave private LDS accumulators.
__global__ __launch_bounds__(256) void rowops(
    const float* __restrict__ logits, const float* __restrict__ gumbel,
    const float* __restrict__ codebook, float* __restrict__ q,
    float* __restrict__ psum_g, int* __restrict__ cnt_g)
{
    __shared__ float psum[4][GV];
    __shared__ int   cnt[4][GV];
    const int tid = threadIdx.x;
    for (int i = tid; i < 4 * GV; i += 256) {
        (&psum[0][0])[i] = 0.f;
        (&cnt[0][0])[i]  = 0;
    }
    __syncthreads();

    const int wave = tid >> 6, lane = tid & 63;
    const int row0 = blockIdx.x * 64;

    for (int r = wave; r < 64; r += 4) {
        const int t = row0 + r;
        const float* lrow = logits + (size_t)t * GV;
        const float* grow = gumbel + (size_t)t * GV;
        float lv[10], gvl[10];
#pragma unroll
        for (int m = 0; m < 10; ++m) {
            lv[m]  = lrow[lane + 64*m];
            gvl[m] = grow[lane + 64*m];
        }
#pragma unroll
        for (int g = 0; g < 2; ++g) {
            float bestl = -3.4e38f; int bli = 0;   // argmax of raw logits (hard codes)
            float bestt = -3.4e38f; int bti = 0;   // argmax of logits+gumbel (training path)
#pragma unroll
            for (int m = 5*g; m < 5*g + 5; ++m) {
                const int col = lane + 64*m;
                const float l  = lv[m];
                const float tv = l + gvl[m];
                if (l  > bestl) { bestl = l;  bli = col; }
                if (tv > bestt) { bestt = tv; bti = col; }
            }
#pragma unroll
            for (int off = 32; off > 0; off >>= 1) {
                const float v2 = __shfl_xor(bestl, off); const int i2 = __shfl_xor(bli, off);
                if (v2 > bestl || (v2 == bestl && i2 < bli)) { bestl = v2; bli = i2; }
                const float t2 = __shfl_xor(bestt, off); const int j2 = __shfl_xor(bti, off);
                if (t2 > bestt || (t2 == bestt && j2 < bti)) { bestt = t2; bti = j2; }
            }
            // softmax of raw logits within group; bestl is the group max
            float s = 0.f;
#pragma unroll
            for (int m = 5*g; m < 5*g + 5; ++m) s += expf(lv[m] - bestl);
#pragma unroll
            for (int off = 32; off > 0; off >>= 1) s += __shfl_xor(s, off);
            const float inv_s = 1.0f / s;
#pragma unroll
            for (int m = 5*g; m < 5*g + 5; ++m)
                psum[wave][lane + 64*m] += expf(lv[m] - bestl) * inv_s;
            if (lane == 0) cnt[wave][bli] += 1;
            // straight-through forward: q row = codebook[bti]
            const float* cbrow = codebook + (size_t)bti * VD;
            float* qdst = q + (size_t)t * 256 + g * VD;
            qdst[lane]      = cbrow[lane];
            qdst[lane + 64] = cbrow[lane + 64];
        }
    }
    __syncthreads();
    for (int i = tid; i < GV; i += 256) {
        atomicAdd(&psum_g[i], psum[0][i] + psum[1][i] + psum[2][i] + psum[3][i]);
        atomicAdd(&cnt_g[i],  cnt[0][i] + cnt[1][i] + cnt[2][i] + cnt[3][i]);
    }
}

// ---------------- tiny kernels ----------------
__global__ void zero_accums(float* psum_g, int* cnt_g)
{
    const int i = threadIdx.x + blockIdx.x * 256;
    if (i < GV) { psum_g[i] = 0.f; cnt_g[i] = 0; }
}

__global__ void finalize(const int* __restrict__ cnt_g, const float* __restrict__ psum_g,
                         float* __restrict__ out_scalars)
{
    const int lane = threadIdx.x;   // 64 threads = 1 wave
    float h[2] = {0.f, 0.f}, p[2] = {0.f, 0.f};
    for (int i = lane; i < GV; i += 64) {
        const int g = i / NV;
        const float hp = (float)cnt_g[i] * INV_BT;
        const float ap = psum_g[i] * INV_BT;
        h[g] -= hp * logf(hp + 1e-7f);
        p[g] -= ap * logf(ap + 1e-7f);
    }
#pragma unroll
    for (int off = 32; off > 0; off >>= 1) {
        h[0] += __shfl_xor(h[0], off); h[1] += __shfl_xor(h[1], off);
        p[0] += __shfl_xor(p[0], off); p[1] += __shfl_xor(p[1], off);
    }
    if (lane == 0) {
        out_scalars[0] = expf(h[0]) + expf(h[1]);   // code_perplexity
        out_scalars[1] = expf(p[0]) + expf(p[1]);   // prob_perplex
    }
}

extern "C" void kernel_launch(void* const* d_in, const int* in_sizes, int n_in,
                              void* d_out, int out_size, void* d_ws, size_t ws_size,
                              hipStream_t stream)
{
    const float* X  = (const float*)d_in[0];   // [64000,1024]
    const float* W  = (const float*)d_in[1];   // [640,1024]
    const float* Bv = (const float*)d_in[2];   // [640]
    const float* CB = (const float*)d_in[3];   // [640,128]
    const float* GU = (const float*)d_in[4];   // [64000,640]

    float* q = (float*)d_out;                                  // [64000,256]
    float* out_scalars = (float*)d_out + (size_t)BT_TOT * 256; // 2 scalars

    char* ws = (char*)d_ws;
    float* psum_g = (float*)ws;                 // 640 floats
    int*   cnt_g  = (int*)(ws + GV * 4);        // 640 ints
    float* logits = (float*)(ws + 8192);        // 64000*640 floats = 163.84 MB

    zero_accums<<<3, 256, 0, stream>>>(psum_g, cnt_g);
    dim3 g1(5, 500);
    gemm_logits<<<g1, 256, 0, stream>>>(X, W, Bv, logits);
    rowops<<<1000, 256, 0, stream>>>(logits, GU, CB, q, psum_g, cnt_g);
    finalize<<<1, 64, 0, stream>>>(cnt_g, psum_g, out_scalars);
}

// Round 2
// 915.547 us; speedup vs baseline: 1.4959x; 1.4959x over previous
//
#include <hip/hip_runtime.h>
#include <cstdint>
#include <cstddef>

#define BT_TOT 64000
#define FIN    1024
#define GV     640
#define NV     320
#define VD     128
#define INV_BT (1.0f/64000.0f)

#define BKF 32
#define LDK 40            // padded LDS row stride (bf16 units): 80 B -> conflict-light b128 reads

typedef __attribute__((ext_vector_type(8))) __bf16 bf16x8;
typedef __attribute__((ext_vector_type(4))) float f32x4;

__device__ inline short f2bf(float x) {            // RNE fp32 -> bf16 bits
    unsigned int u = __float_as_uint(x);
    unsigned int r = (u + 0x7fffu + ((u >> 16) & 1u)) >> 16;
    return (short)r;
}
__device__ inline float bf2f(short h) {
    return __uint_as_float(((unsigned int)(unsigned short)h) << 16);
}
__device__ inline bf16x8 ld_frag(const short* p) {
    union { uint4 u; bf16x8 v; } t;
    t.u = *(const uint4*)p;
    return t.v;
}

// ---------- prep: split W into bf16 hi/lo, zero global accumulators ----------
__global__ __launch_bounds__(256) void prep(
    const float* __restrict__ W, short* __restrict__ Whi, short* __restrict__ Wlo,
    float* __restrict__ psum_g, int* __restrict__ cnt_g)
{
    const int t = blockIdx.x * 256 + threadIdx.x;      // 640 blocks -> 163840 threads
    if (t < GV) { psum_g[t] = 0.f; cnt_g[t] = 0; }
    const size_t e = (size_t)t * 4;
    const float4 w = *(const float4*)(W + e);
    float ws4[4] = {w.x, w.y, w.z, w.w};
    short h[4], l[4];
#pragma unroll
    for (int i = 0; i < 4; ++i) {
        h[i] = f2bf(ws4[i]);
        l[i] = f2bf(ws4[i] - bf2f(h[i]));
    }
    *(short4*)(Whi + e) = make_short4(h[0], h[1], h[2], h[3]);
    *(short4*)(Wlo + e) = make_short4(l[0], l[1], l[2], l[3]);
}

// ---------- fused: bf16-triple MFMA GEMM + argmax/softmax/gather epilogue ----------
// 500 blocks x 512 threads. Block = 128 rows x 640 cols. 8 waves: mw=wave&3 (32-row
// stripe), nw=wave>>2 (320-col group). Wave tile 32x320 = 2 Mt x 20 Nt of 16x16x32.
__global__ __launch_bounds__(512, 2) void fused(
    const float* __restrict__ X, const short* __restrict__ Whi, const short* __restrict__ Wlo,
    const float* __restrict__ bias, const float* __restrict__ gumbel,
    const float* __restrict__ codebook, float* __restrict__ q,
    float* __restrict__ psum_g, int* __restrict__ cnt_g)
{
    __shared__ short Ah[128 * LDK], Al[128 * LDK];     // 10 KB each
    __shared__ short Bh[640 * LDK], Bl[640 * LDK];     // 50 KB each
    __shared__ float psum_l[GV];
    __shared__ int   cnt_l[GV];
    __shared__ int   gidx[128 * 2];

    const int tid  = threadIdx.x;
    const int wave = tid >> 6, lane = tid & 63;
    const int mw = wave & 3, nw = wave >> 2;
    const int quad = lane >> 4, cl = lane & 15;
    const int row0 = blockIdx.x * 128;

    for (int i = tid; i < GV; i += 512) { psum_l[i] = 0.f; cnt_l[i] = 0; }

    f32x4 acc[2][20];
#pragma unroll
    for (int mt = 0; mt < 2; ++mt)
#pragma unroll
        for (int nt = 0; nt < 20; ++nt) acc[mt][nt] = (f32x4){0.f, 0.f, 0.f, 0.f};

    for (int k0 = 0; k0 < FIN; k0 += BKF) {
        __syncthreads();
        // stage X tile (fp32 -> hi/lo bf16): thread -> row tid>>2, k-chunk (tid&3)*8
        {
            const int r = tid >> 2, kq = (tid & 3) * 8;
            const float* src = X + (size_t)(row0 + r) * FIN + k0 + kq;
            const float4 x0 = *(const float4*)src;
            const float4 x1 = *(const float4*)(src + 4);
            float xs[8] = {x0.x, x0.y, x0.z, x0.w, x1.x, x1.y, x1.z, x1.w};
            short hi[8], lo[8];
#pragma unroll
            for (int e = 0; e < 8; ++e) {
                hi[e] = f2bf(xs[e]);
                lo[e] = f2bf(xs[e] - bf2f(hi[e]));
            }
            *(uint4*)&Ah[r * LDK + kq] = *(uint4*)hi;
            *(uint4*)&Al[r * LDK + kq] = *(uint4*)lo;
        }
        // stage W tile (already bf16 pairs): 2560 16B-chunks / 512 threads = 5 each
#pragma unroll
        for (int i = 0; i < 5; ++i) {
            const int task = tid + 512 * i;
            const int r = task >> 2, kq = (task & 3) * 8;
            const size_t goff = (size_t)r * FIN + k0 + kq;
            *(uint4*)&Bh[r * LDK + kq] = *(const uint4*)(Whi + goff);
            *(uint4*)&Bl[r * LDK + kq] = *(const uint4*)(Wlo + goff);
        }
        __syncthreads();

        bf16x8 ah[2], al[2];
#pragma unroll
        for (int mt = 0; mt < 2; ++mt) {
            const int rowa = mw * 32 + mt * 16 + cl;
            ah[mt] = ld_frag(&Ah[rowa * LDK + quad * 8]);
            al[mt] = ld_frag(&Al[rowa * LDK + quad * 8]);
        }
#pragma unroll
        for (int nt = 0; nt < 20; ++nt) {
            const int coln = nw * 320 + nt * 16 + cl;
            const bf16x8 bh = ld_frag(&Bh[coln * LDK + quad * 8]);
            const bf16x8 bl = ld_frag(&Bl[coln * LDK + quad * 8]);
            acc[0][nt] = __builtin_amdgcn_mfma_f32_16x16x32_bf16(ah[0], bh, acc[0][nt], 0, 0, 0);
            acc[1][nt] = __builtin_amdgcn_mfma_f32_16x16x32_bf16(ah[1], bh, acc[1][nt], 0, 0, 0);
            acc[0][nt] = __builtin_amdgcn_mfma_f32_16x16x32_bf16(al[0], bh, acc[0][nt], 0, 0, 0);
            acc[1][nt] = __builtin_amdgcn_mfma_f32_16x16x32_bf16(al[1], bh, acc[1][nt], 0, 0, 0);
            acc[0][nt] = __builtin_amdgcn_mfma_f32_16x16x32_bf16(ah[0], bl, acc[0][nt], 0, 0, 0);
            acc[1][nt] = __builtin_amdgcn_mfma_f32_16x16x32_bf16(ah[1], bl, acc[1][nt], 0, 0, 0);
        }
    }

    // bias add (D layout: col = cl, row = quad*4+reg)
#pragma unroll
    for (int nt = 0; nt < 20; ++nt) {
        const float bv = bias[nw * 320 + nt * 16 + cl];
#pragma unroll
        for (int mt = 0; mt < 2; ++mt)
#pragma unroll
            for (int r = 0; r < 4; ++r) acc[mt][nt][r] += bv;
    }

    // per-row reductions: each (mt,reg) handles 4 rows (one per quad) in parallel
    float psum_part[20];
#pragma unroll
    for (int nt = 0; nt < 20; ++nt) psum_part[nt] = 0.f;

#pragma unroll
    for (int mt = 0; mt < 2; ++mt) {
#pragma unroll
        for (int reg = 0; reg < 4; ++reg) {
            const int row_l = mw * 32 + mt * 16 + quad * 4 + reg;
            const float* gp = gumbel + (size_t)(row0 + row_l) * GV + nw * 320;
            float bestv = -3.4e38f, gbestv = -3.4e38f;
            int bestc = 0, gbestc = 0;
#pragma unroll
            for (int nt = 0; nt < 20; ++nt) {
                const float v = acc[mt][nt][reg];
                const int c = nt * 16 + cl;
                const float tv = v + gp[c];
                if (v > bestv)  { bestv = v;  bestc = c; }
                if (tv > gbestv){ gbestv = tv; gbestc = c; }
            }
#pragma unroll
            for (int off = 1; off < 16; off <<= 1) {
                const float v2 = __shfl_xor(bestv, off); const int c2 = __shfl_xor(bestc, off);
                if (v2 > bestv || (v2 == bestv && c2 < bestc)) { bestv = v2; bestc = c2; }
                const float g2 = __shfl_xor(gbestv, off); const int gc2 = __shfl_xor(gbestc, off);
                if (g2 > gbestv || (g2 == gbestv && gc2 < gbestc)) { gbestv = g2; gbestc = gc2; }
            }
            float e[20], s = 0.f;
#pragma unroll
            for (int nt = 0; nt < 20; ++nt) { e[nt] = __expf(acc[mt][nt][reg] - bestv); s += e[nt]; }
#pragma unroll
            for (int off = 1; off < 16; off <<= 1) s += __shfl_xor(s, off);
            const float inv_s = 1.0f / s;
#pragma unroll
            for (int nt = 0; nt < 20; ++nt) psum_part[nt] += e[nt] * inv_s;
            if (cl == 0) {
                atomicAdd(&cnt_l[nw * 320 + bestc], 1);
                gidx[row_l * 2 + nw] = nw * 320 + gbestc;
            }
        }
    }

    // fold psum over the 4 quads (rows), then into block-level LDS accumulator
#pragma unroll
    for (int nt = 0; nt < 20; ++nt) {
        float v = psum_part[nt];
        v += __shfl_xor(v, 16);
        v += __shfl_xor(v, 32);
        if (quad == 0) atomicAdd(&psum_l[nw * 320 + nt * 16 + cl], v);
    }
    __syncthreads();

    // q gather: 128 rows x 2 groups x 128 dims; 2 threads per (row,group)
    {
        const int unit = tid >> 1, half = tid & 1;
        const int row = unit >> 1, g = unit & 1;
        const int idx = gidx[row * 2 + g];
        const float4* src = (const float4*)(codebook + (size_t)idx * VD + half * 64);
        float4* dst = (float4*)(q + (size_t)(row0 + row) * 256 + g * VD + half * 64);
#pragma unroll
        for (int i = 0; i < 16; ++i) dst[i] = src[i];
    }
    // flush block accumulators
    for (int i = tid; i < GV; i += 512) {
        atomicAdd(&psum_g[i], psum_l[i]);
        atomicAdd(&cnt_g[i], cnt_l[i]);
    }
}

// ---------- finalize ----------
__global__ void finalize(const int* __restrict__ cnt_g, const float* __restrict__ psum_g,
                         float* __restrict__ out_scalars)
{
    const int lane = threadIdx.x;   // 64 threads = 1 wave
    float h[2] = {0.f, 0.f}, p[2] = {0.f, 0.f};
    for (int i = lane; i < GV; i += 64) {
        const int g = i / NV;
        const float hp = (float)cnt_g[i] * INV_BT;
        const float ap = psum_g[i] * INV_BT;
        h[g] -= hp * logf(hp + 1e-7f);
        p[g] -= ap * logf(ap + 1e-7f);
    }
#pragma unroll
    for (int off = 32; off > 0; off >>= 1) {
        h[0] += __shfl_xor(h[0], off); h[1] += __shfl_xor(h[1], off);
        p[0] += __shfl_xor(p[0], off); p[1] += __shfl_xor(p[1], off);
    }
    if (lane == 0) {
        out_scalars[0] = expf(h[0]) + expf(h[1]);
        out_scalars[1] = expf(p[0]) + expf(p[1]);
    }
}

extern "C" void kernel_launch(void* const* d_in, const int* in_sizes, int n_in,
                              void* d_out, int out_size, void* d_ws, size_t ws_size,
                              hipStream_t stream)
{
    const float* X  = (const float*)d_in[0];   // [64000,1024]
    const float* W  = (const float*)d_in[1];   // [640,1024]
    const float* Bv = (const float*)d_in[2];   // [640]
    const float* CB = (const float*)d_in[3];   // [640,128]
    const float* GU = (const float*)d_in[4];   // [64000,640]

    float* q = (float*)d_out;                                  // [64000,256]
    float* out_scalars = (float*)d_out + (size_t)BT_TOT * 256; // 2 scalars

    char* ws = (char*)d_ws;
    float* psum_g = (float*)ws;                       // 640 floats
    int*   cnt_g  = (int*)(ws + 4096);                // 640 ints
    short* Whi    = (short*)(ws + 8192);              // 640*1024 bf16 = 1.31 MB
    short* Wlo    = (short*)(ws + 8192 + 2 * GV * FIN);

    prep<<<640, 256, 0, stream>>>(W, Whi, Wlo, psum_g, cnt_g);
    fused<<<500, 512, 0, stream>>>(X, Whi, Wlo, Bv, GU, CB, q, psum_g, cnt_g);
    finalize<<<1, 64, 0, stream>>>(cnt_g, psum_g, out_scalars);
}